// Round 9
// baseline (70.187 us; speedup 1.0000x reference)
//
#include <hip/hip_runtime.h>

#define L_DIM 2048
#define H_DIM 8
#define E_DIM 64
#define C2 0.18033688f  // 0.125 * log2(e)

typedef __attribute__((ext_vector_type(4))) float f32x4;
typedef __attribute__((ext_vector_type(4))) short short4v;
typedef __attribute__((ext_vector_type(8))) short short8;

typedef const void __attribute__((address_space(1)))* gp1;
typedef void __attribute__((address_space(3)))* lp3;
__device__ __forceinline__ void gl_lds16(const void* g, void* l) {
  __builtin_amdgcn_global_load_lds((gp1)g, (lp3)l, 16, 0, 0);
}

__device__ __forceinline__ unsigned short f2bf(float f) {
  union { float f; unsigned u; } c; c.f = f;
  unsigned u = c.u;
  return (unsigned short)((u + 0x7fffu + ((u >> 16) & 1u)) >> 16);
}

__device__ __forceinline__ unsigned cvtpk(float lo, float hi) {
  unsigned r;
  asm("v_cvt_pk_bf16_f32 %0, %1, %2" : "=v"(r) : "v"(lo), "v"(hi));
  return r;
}

// Swizzled 64x64-bf16 LDS tile: row stride 128B, 16B chunk c at phys c^(row&7).
__device__ __forceinline__ short8 read_frag(const unsigned char* base, int row, int ec, int g) {
  int p = (row & 7) << 1;
  short4v lo = *(const short4v*)(base + row * 128 + (((8 * ec + g) ^ p) << 3));
  short4v hi = *(const short4v*)(base + row * 128 + (((8 * ec + 4 + g) ^ p) << 3));
  return __builtin_shufflevector(lo, hi, 0, 1, 2, 3, 4, 5, 6, 7);
}

// Pre-pass. Staged layouts (per bh, 32 tiles of 64 rows x 128B; 16B chunk c of a
// row stored at chunk c^(row&7)) so attn can global_load_lds linearly.
__global__ __launch_bounds__(256) void prep_kernel(
    const float* __restrict__ qin, const float* __restrict__ kin, const float* __restrict__ vin,
    unsigned short* __restrict__ qstg, unsigned short* __restrict__ kstg,
    unsigned short* __restrict__ vstg, float* __restrict__ qn2, float* __restrict__ kn2,
    int* __restrict__ kn2max) {
  __shared__ unsigned short vlds[64][68];
  __shared__ float redm[4];
  int bh = blockIdx.y, z = blockIdx.z;
  int b = bh >> 3, h = bh & 7;
  int r0 = blockIdx.x * 64;
  int t = threadIdx.x;
  int row = t >> 2, quad = t & 3;

  const float* src = (z == 0) ? qin : (z == 1) ? kin : vin;
  const float* rp = src + (((size_t)(b * L_DIM + r0 + row) * H_DIM + h) * E_DIM + quad * 16);
  f32x4 fv[4];
#pragma unroll
  for (int i = 0; i < 4; ++i) fv[i] = ((const f32x4*)rp)[i];
  float vals[16];
#pragma unroll
  for (int i = 0; i < 16; ++i) vals[i] = fv[i / 4][i % 4];

  if (z < 2) {
    unsigned short* dst = (z == 0) ? qstg : kstg;
    float* n2 = (z == 0) ? qn2 : kn2;
    float ss = 0.f;
#pragma unroll
    for (int i = 0; i < 16; ++i) ss = fmaf(vals[i], vals[i], ss);
    ss += __shfl_xor(ss, 1);
    ss += __shfl_xor(ss, 2);
    unsigned pk[8];
#pragma unroll
    for (int i = 0; i < 8; ++i)
      pk[i] = (unsigned)f2bf(vals[2 * i]) | ((unsigned)f2bf(vals[2 * i + 1]) << 16);
    size_t base_el = (size_t)bh * L_DIM * E_DIM + (size_t)blockIdx.x * 4096 + row * 64;
    int s7 = row & 7;
    int d0 = (2 * quad) ^ s7, d1 = (2 * quad + 1) ^ s7;
    *(uint4*)(dst + base_el + d0 * 8) = make_uint4(pk[0], pk[1], pk[2], pk[3]);
    *(uint4*)(dst + base_el + d1 * 8) = make_uint4(pk[4], pk[5], pk[6], pk[7]);
    if (quad == 0) n2[(size_t)bh * L_DIM + r0 + row] = ss;
    if (z == 1) {
      float mx = ss;
#pragma unroll
      for (int d = 4; d < 64; d <<= 1) mx = fmaxf(mx, __shfl_xor(mx, d));
      if ((t & 63) == 0) redm[t >> 6] = mx;
      __syncthreads();
      if (t == 0) {
        float bm = fmaxf(fmaxf(redm[0], redm[1]), fmaxf(redm[2], redm[3]));
        atomicMax(kn2max + bh, __float_as_int(bm));
      }
    }
  } else {
#pragma unroll
    for (int i = 0; i < 16; ++i) vlds[row][quad * 16 + i] = f2bf(vals[i]);
    __syncthreads();
    int e = t >> 2, sq = t & 3;
    unsigned pk[8];
#pragma unroll
    for (int i = 0; i < 8; ++i)
      pk[i] = (unsigned)vlds[sq * 16 + 2 * i][e] | ((unsigned)vlds[sq * 16 + 2 * i + 1][e] << 16);
    size_t base_el = (size_t)bh * E_DIM * L_DIM + (size_t)blockIdx.x * 4096 + e * 64;
    int s7 = e & 7;
    int d0 = (2 * sq) ^ s7, d1 = (2 * sq + 1) ^ s7;
    *(uint4*)(vstg + base_el + d0 * 8) = make_uint4(pk[0], pk[1], pk[2], pk[3]);
    *(uint4*)(vstg + base_el + d1 * 8) = make_uint4(pk[4], pk[5], pk[6], pk[7]);
  }
}

struct B0 { static constexpr int value = 0; };
struct B1 { static constexpr int value = 1; };

// One block = 64 q rows of one (b,h) x ONE s-half (16 tiles); 4 waves.
// Verbatim R7 skeleton per block (stage -> compute -> __syncthreads, dbuf).
// Writes unnormalized partials (o, l); fixed-m softmax => partials add exactly.
// LDS 40960 B -> 4 blocks/CU; grid 1024 -> 16 waves/CU (2x R7's TLP).
__global__ __launch_bounds__(256, 4) void attn_kernel(
    const unsigned short* __restrict__ qst, const unsigned short* __restrict__ kst,
    const unsigned short* __restrict__ vst, const float* __restrict__ qn2g,
    const float* __restrict__ kn2g, const int* __restrict__ kn2maxg,
    float* __restrict__ opart, float* __restrict__ lpart) {
  __shared__ __align__(16) unsigned char Qs[8192];
  __shared__ __align__(16) unsigned char Ks[2][8192];
  __shared__ __align__(16) unsigned char Vs[2][8192];

  // XCD swizzle: 1024 blocks, 128-chunk per XCD (bijective, 1024%8==0).
  int flat = blockIdx.x;
  int sw = (flat & 7) * 128 + (flat >> 3);
  int bh = sw >> 6;
  int qt = (sw >> 1) & 31;
  int sh = sw & 1;
  int q0 = qt * 64;
  int tb = sh * 16;  // this block's s-tile base

  int t = threadIdx.x;
  int lane = t & 63, w = t >> 6;
  int l15 = lane & 15, g = lane >> 4;

  const char* kbase = (const char*)kst + (size_t)bh * (L_DIM * E_DIM * 2);
  const char* vbase = (const char*)vst + (size_t)bh * (L_DIM * E_DIM * 2);
  const float* kn2p = kn2g + (size_t)bh * L_DIM;

  auto stage = [&](auto SBC, int tile) {
    constexpr int SB = decltype(SBC)::value;
    const char* ks = kbase + (size_t)tile * 8192 + t * 16;
    const char* vs = vbase + (size_t)tile * 8192 + t * 16;
    gl_lds16(ks, (char*)Ks[SB] + t * 16);
    gl_lds16(ks + 4096, (char*)Ks[SB] + 4096 + t * 16);
    gl_lds16(vs, (char*)Vs[SB] + t * 16);
    gl_lds16(vs + 4096, (char*)Vs[SB] + 4096 + t * 16);
  };

  {  // prologue: Q tile + first K/V tile; __syncthreads drains all
    const char* qb = (const char*)qst + (size_t)bh * (L_DIM * E_DIM * 2) +
                     (size_t)qt * 8192;
    gl_lds16(qb + t * 16, Qs + t * 16);
    gl_lds16(qb + 4096 + t * 16, Qs + 4096 + t * 16);
  }
  stage(B0{}, tb);
  float qn2v = qn2g[(size_t)bh * L_DIM + q0 + w * 16 + l15];
  float mneg = -(C2 * __builtin_amdgcn_sqrtf(qn2v * __int_as_float(kn2maxg[bh])));
  __syncthreads();

  short8 qf0 = read_frag(Qs, w * 16 + l15, 0, g);
  short8 qf1 = read_frag(Qs, w * 16 + l15, 1, g);

  f32x4 o[4];
#pragma unroll
  for (int i = 0; i < 4; ++i) o[i] = (f32x4){0.f, 0.f, 0.f, 0.f};
  float lrun = 0.f;

  auto compute = [&](auto BC, int tile) {
    constexpr int B = decltype(BC)::value;
    // ---- QK^T ----
    f32x4 c_[4];
#pragma unroll
    for (int st = 0; st < 4; ++st) {
      short8 kf0 = read_frag(Ks[B], st * 16 + l15, 0, g);
      short8 kf1 = read_frag(Ks[B], st * 16 + l15, 1, g);
      f32x4 c = (f32x4){0.f, 0.f, 0.f, 0.f};
      c = __builtin_amdgcn_mfma_f32_16x16x32_bf16(kf0, qf0, c, 0, 0, 0);
      c = __builtin_amdgcn_mfma_f32_16x16x32_bf16(kf1, qf1, c, 0, 0, 0);
      c_[st] = c;
    }
    // ---- scores (k2 via direct global f32x4, L1/L2-hot; R4-proven) ----
    float p_[4][4];
#pragma unroll
    for (int st = 0; st < 4; ++st) {
      f32x4 k2 = *(const f32x4*)(kn2p + tile * 64 + st * 16 + 4 * g);
#pragma unroll
      for (int r = 0; r < 4; ++r) {
        float w2 = fmaf(qn2v, k2[r], -(c_[st][r] * c_[st][r]));
        float s_ = __builtin_amdgcn_sqrtf(fmaxf(w2, 0.f));
        float p = __builtin_amdgcn_exp2f(fmaf(C2, s_, mneg));
        p_[st][r] = p;
        lrun += p;
      }
    }
    // ---- pack P to bf16 ----
    union U8 { unsigned u[4]; short8 s; } a_, b_;
    a_.u[0] = cvtpk(p_[0][0], p_[0][1]);
    a_.u[1] = cvtpk(p_[0][2], p_[0][3]);
    a_.u[2] = cvtpk(p_[1][0], p_[1][1]);
    a_.u[3] = cvtpk(p_[1][2], p_[1][3]);
    b_.u[0] = cvtpk(p_[2][0], p_[2][1]);
    b_.u[1] = cvtpk(p_[2][2], p_[2][3]);
    b_.u[2] = cvtpk(p_[3][0], p_[3][1]);
    b_.u[3] = cvtpk(p_[3][2], p_[3][3]);
    // ---- PV ----
#pragma unroll
    for (int et = 0; et < 4; ++et) {
      short8 vf0 = read_frag(Vs[B], et * 16 + l15, 0, g);
      short8 vf1 = read_frag(Vs[B], et * 16 + l15, 1, g);
      o[et] = __builtin_amdgcn_mfma_f32_16x16x32_bf16(vf0, a_.s, o[et], 0, 0, 0);
      o[et] = __builtin_amdgcn_mfma_f32_16x16x32_bf16(vf1, b_.s, o[et], 0, 0, 0);
    }
  };

  for (int it = 0; it < 16; it += 2) {
    stage(B1{}, tb + it + 1);
    compute(B0{}, tb + it);
    __syncthreads();
    if (it + 2 < 16) stage(B0{}, tb + it + 2);
    compute(B1{}, tb + it + 1);
    __syncthreads();
  }

  // ---- write unnormalized partials (exact combine: fixed m) ----
  lrun += __shfl_xor(lrun, 16);
  lrun += __shfl_xor(lrun, 32);
  int slot = (bh * 32 + qt) * 2 + sh;
  float* op = opart + (size_t)slot * 4096 + (w * 16 + l15) * 64;
#pragma unroll
  for (int et = 0; et < 4; ++et) *(f32x4*)(op + 16 * et + 4 * g) = o[et];
  if (lane < 16) lpart[slot * 64 + w * 16 + lane] = lrun;
}

// out[b][l][h][e] = (o0 + o1) / (l0 + l1)
__global__ __launch_bounds__(256) void comb_kernel(
    const float* __restrict__ opart, const float* __restrict__ lpart,
    float* __restrict__ outp) {
  int blk = blockIdx.x;  // 512 = bh*32 + qt
  int bh = blk >> 5, qt = blk & 31;
  int b = bh >> 3, h = bh & 7;
  int t = threadIdx.x;
  int r = t >> 2, ec = t & 3;
  const float* p0 = opart + ((size_t)blk * 2) * 4096 + r * 64 + ec * 16;
  const float* p1 = p0 + 4096;
  float l = lpart[blk * 2 * 64 + r] + lpart[(blk * 2 + 1) * 64 + r];
  float inv = 1.f / l;
  size_t ob = (((size_t)(b * L_DIM + qt * 64 + r)) * H_DIM + h) * E_DIM + ec * 16;
#pragma unroll
  for (int i = 0; i < 4; ++i) {
    f32x4 a = ((const f32x4*)p0)[i];
    f32x4 c = ((const f32x4*)p1)[i];
    f32x4 rr = (a + c) * inv;
    *(f32x4*)(outp + ob + 4 * i) = rr;
  }
}

extern "C" void kernel_launch(void* const* d_in, const int* in_sizes, int n_in,
                              void* d_out, int out_size, void* d_ws, size_t ws_size,
                              hipStream_t stream) {
  const float* q = (const float*)d_in[0];
  const float* k = (const float*)d_in[1];
  const float* v = (const float*)d_in[2];
  float* out = (float*)d_out;
  unsigned char* ws = (unsigned char*)d_ws;
  unsigned short* qstg = (unsigned short*)(ws);
  unsigned short* kstg = (unsigned short*)(ws + ((size_t)4 << 20));
  unsigned short* vstg = (unsigned short*)(ws + ((size_t)8 << 20));
  float* qn2 = (float*)(ws + ((size_t)12 << 20));
  float* kn2 = (float*)(ws + ((size_t)12 << 20) + ((size_t)256 << 10));
  int* kn2max = (int*)(ws + ((size_t)12 << 20) + ((size_t)512 << 10));
  float* opart = (float*)(ws + ((size_t)13 << 20));                    // 16 MB
  float* lpart = (float*)(ws + ((size_t)29 << 20));                    // 256 KB

  hipMemsetAsync(kn2max, 0, 16 * sizeof(int), stream);
  dim3 pg(32, 16, 3);
  prep_kernel<<<pg, 256, 0, stream>>>(q, k, v, qstg, kstg, vstg, qn2, kn2, kn2max);
  attn_kernel<<<1024, 256, 0, stream>>>(qstg, kstg, vstg, qn2, kn2, kn2max, opart, lpart);
  comb_kernel<<<512, 256, 0, stream>>>(opart, lpart, out);
}